// Round 1
// baseline (200.399 us; speedup 1.0000x reference)
//
#include <hip/hip_runtime.h>
#include <math.h>

// Problem constants (B, L, D) = (8, 4096, 1024)
#define BB 8
#define LL 4096
#define DD 1024
#define LM1 4095   // number of deltas per batch
#define LM2 4094   // number of delta_increase terms per batch
#define CHUNK 32
#define NCHUNK 128 // ceil(LM1 / CHUNK)

// Kernel 1: delta[b,i] = || states[b,i+1,:] - states[b,i,:] ||_2
// One block handles CHUNK consecutive deltas for one batch (reads CHUNK+1 rows,
// reusing each interior row once -> ~1.03x total read of states).
// 256 threads x float4 = 1024 floats = exactly one row, fully coalesced.
__global__ __launch_bounds__(256) void delta_kernel(const float* __restrict__ states,
                                                    float* __restrict__ delta) {
    const int bid = blockIdx.x;
    const int b = bid / NCHUNK;
    const int c = bid % NCHUNK;
    const int i0 = c * CHUNK;
    const int iend = (i0 + CHUNK < LM1) ? (i0 + CHUNK) : LM1; // deltas [i0, iend)
    const int tid = threadIdx.x;
    const int lane = tid & 63;
    const int wid = tid >> 6;

    const float4* base = (const float4*)states + (size_t)b * LL * (DD / 4) + tid;

    __shared__ float lds[4];

    float4 prev = base[(size_t)i0 * (DD / 4)];
    for (int i = i0; i < iend; ++i) {
        float4 cur = base[(size_t)(i + 1) * (DD / 4)];
        float dx = cur.x - prev.x;
        float dy = cur.y - prev.y;
        float dz = cur.z - prev.z;
        float dw = cur.w - prev.w;
        float s = dx * dx + dy * dy + dz * dz + dw * dw;
        #pragma unroll
        for (int off = 32; off > 0; off >>= 1) s += __shfl_down(s, off);
        if (lane == 0) lds[wid] = s;
        __syncthreads();
        if (tid == 0) delta[b * LM1 + i] = sqrtf(lds[0] + lds[1] + lds[2] + lds[3]);
        __syncthreads();
        prev = cur;
    }
}

// Kernel 2: per-block partial sums of
//   num += relu(delta[t+1]-delta[t]) * mask[b,t+2] * weight(b,t)
//   den += mask[b,t+2]
// Deterministic: each block writes its partial to its own slot.
__global__ __launch_bounds__(256) void weighted_kernel(const float* __restrict__ delta,
                                                       const float* __restrict__ rmask,
                                                       const int* __restrict__ rpos,
                                                       float* __restrict__ pnum,
                                                       float* __restrict__ pden) {
    const int tid = threadIdx.x;
    const int gid = blockIdx.x * blockDim.x + tid;
    const int stride = gridDim.x * blockDim.x;
    const int lane = tid & 63;
    const int wid = tid >> 6;

    float num = 0.0f, den = 0.0f;
    for (int b = 0; b < BB; ++b) {
        const int rp = rpos[b];
        const float* __restrict__ db = delta + b * LM1;
        const float* __restrict__ mb = rmask + b * LL + 2;
        for (int t = gid; t < LM2; t += stride) {
            float inc = db[t + 1] - db[t];
            inc = inc > 0.0f ? inc : 0.0f;
            float m = mb[t];
            int dist = rp - t - 2;
            if (dist < 0) dist = 0;
            float w = (dist < 5) ? (2.0f + (float)(5 - dist) * 0.5f) : 1.0f;
            num += inc * m * w;
            den += m;
        }
    }
    #pragma unroll
    for (int off = 32; off > 0; off >>= 1) {
        num += __shfl_down(num, off);
        den += __shfl_down(den, off);
    }
    __shared__ float ln[4], ld[4];
    if (lane == 0) { ln[wid] = num; ld[wid] = den; }
    __syncthreads();
    if (tid == 0) {
        pnum[blockIdx.x] = ln[0] + ln[1] + ln[2] + ln[3];
        pden[blockIdx.x] = ld[0] + ld[1] + ld[2] + ld[3];
    }
}

// Kernel 3: reduce the 64 partials in one wave and divide.
__global__ __launch_bounds__(64) void final_kernel(const float* __restrict__ pnum,
                                                   const float* __restrict__ pden,
                                                   float* __restrict__ out) {
    const int lane = threadIdx.x;
    float n = pnum[lane];
    float d = pden[lane];
    #pragma unroll
    for (int off = 32; off > 0; off >>= 1) {
        n += __shfl_down(n, off);
        d += __shfl_down(d, off);
    }
    if (lane == 0) out[0] = n / (d + 1e-9f);
}

extern "C" void kernel_launch(void* const* d_in, const int* in_sizes, int n_in,
                              void* d_out, int out_size, void* d_ws, size_t ws_size,
                              hipStream_t stream) {
    const float* states = (const float*)d_in[0];
    const float* rmask  = (const float*)d_in[1];
    const int*   rpos   = (const int*)d_in[2];
    float* out = (float*)d_out;

    float* ws    = (float*)d_ws;
    float* delta = ws;                 // BB*LM1 = 32760 floats (pad to 32768)
    float* pnum  = ws + 32768;         // 64 floats
    float* pden  = ws + 32768 + 64;    // 64 floats

    delta_kernel<<<BB * NCHUNK, 256, 0, stream>>>(states, delta);
    weighted_kernel<<<64, 256, 0, stream>>>(delta, rmask, rpos, pnum, pden);
    final_kernel<<<1, 64, 0, stream>>>(pnum, pden, out);
}

// Round 2
// 197.641 us; speedup vs baseline: 1.0140x; 1.0140x over previous
//
#include <hip/hip_runtime.h>
#include <math.h>

// Problem constants (B, L, D) = (8, 4096, 1024)
#define BB 8
#define LL 4096
#define DD 1024
#define LM1 4095   // deltas per batch
#define LM2 4094   // delta_increase terms per batch
#define CHUNK 16   // increases per wave
#define NDELTA 17  // CHUNK+1 deltas per wave
#define ROWS 18    // CHUNK+2 rows per wave
#define NCH 256    // chunks per batch = ceil(LM2/CHUNK)
#define NBLK 512   // (BB*NCH) waves / 4 waves-per-block

// One wave handles CHUNK consecutive delta_increases for one batch:
//   - loads ROWS consecutive state rows (4 x float4 per lane per row, coalesced)
//   - accumulates NDELTA per-lane partial dot products in registers (no LDS,
//     no barriers inside the loop -> all 72 loads are independent and pipeline)
//   - one butterfly reduce at the end materializes the deltas in-lane
//   - increases * mask * approach_weight summed in-wave
// Block (4 waves) writes one deterministic partial -> no atomics.
__global__ __launch_bounds__(256) void fused_kernel(const float* __restrict__ states,
                                                    const float* __restrict__ rmask,
                                                    const int* __restrict__ rpos,
                                                    float* __restrict__ pnum,
                                                    float* __restrict__ pden) {
    const int tid = threadIdx.x;
    const int lane = tid & 63;
    const int wid = tid >> 6;
    const int w = blockIdx.x * 4 + wid;  // global wave id, 0..2047
    const int b = w >> 8;                // w / NCH
    const int c = w & (NCH - 1);         // w % NCH
    const int t0 = c * CHUNK;            // first increase index, <= 4080

    const float4* base = (const float4*)states + (size_t)b * (LL * (DD / 4)) + lane;

    float partial[NDELTA];

    float4 p0, p1, p2, p3;
    {
        const float4* rp_ = base + (size_t)t0 * (DD / 4);
        p0 = rp_[0]; p1 = rp_[64]; p2 = rp_[128]; p3 = rp_[192];
    }
    #pragma unroll
    for (int r = 1; r < ROWS; ++r) {
        int row = t0 + r;
        if (row > LL - 1) row = LL - 1;  // clamp (dup row -> masked out later)
        const float4* rp_ = base + (size_t)row * (DD / 4);
        float4 c0 = rp_[0], c1 = rp_[64], c2 = rp_[128], c3 = rp_[192];
        float s = 0.0f, d;
        d = c0.x - p0.x; s += d * d;
        d = c0.y - p0.y; s += d * d;
        d = c0.z - p0.z; s += d * d;
        d = c0.w - p0.w; s += d * d;
        d = c1.x - p1.x; s += d * d;
        d = c1.y - p1.y; s += d * d;
        d = c1.z - p1.z; s += d * d;
        d = c1.w - p1.w; s += d * d;
        d = c2.x - p2.x; s += d * d;
        d = c2.y - p2.y; s += d * d;
        d = c2.z - p2.z; s += d * d;
        d = c2.w - p2.w; s += d * d;
        d = c3.x - p3.x; s += d * d;
        d = c3.y - p3.y; s += d * d;
        d = c3.z - p3.z; s += d * d;
        d = c3.w - p3.w; s += d * d;
        partial[r - 1] = s;
        p0 = c0; p1 = c1; p2 = c2; p3 = c3;
    }

    // Butterfly-reduce each partial across the 64 lanes; lane d keeps delta d.
    float dval = 0.0f;
    #pragma unroll
    for (int d2 = 0; d2 < NDELTA; ++d2) {
        float s = partial[d2];
        #pragma unroll
        for (int off = 1; off < 64; off <<= 1) s += __shfl_xor(s, off);
        if (lane == d2) dval = sqrtf(s);
    }
    float dnext = __shfl_down(dval, 1);  // lane j gets delta[t0+j+1]

    const int t = t0 + lane;
    const bool valid = (lane < CHUNK) && (t < LM2);
    float inc = dnext - dval;
    inc = inc > 0.0f ? inc : 0.0f;
    int midx = b * LL + t + 2;
    if (midx > BB * LL - 1) midx = BB * LL - 1;  // safe even if speculated
    float m = valid ? rmask[midx] : 0.0f;
    const int rp = rpos[b];
    int dist = rp - t - 2;
    if (dist < 0) dist = 0;
    const float wgt = (dist < 5) ? (2.0f + (float)(5 - dist) * 0.5f) : 1.0f;
    float num = valid ? inc * m * wgt : 0.0f;
    float den = m;  // already 0 when invalid

    #pragma unroll
    for (int off = 32; off > 0; off >>= 1) {
        num += __shfl_down(num, off);
        den += __shfl_down(den, off);
    }
    __shared__ float ln[4], ld[4];
    if (lane == 0) { ln[wid] = num; ld[wid] = den; }
    __syncthreads();
    if (tid == 0) {
        pnum[blockIdx.x] = ln[0] + ln[1] + ln[2] + ln[3];
        pden[blockIdx.x] = ld[0] + ld[1] + ld[2] + ld[3];
    }
}

// Reduce the NBLK partials in one block and divide.
__global__ __launch_bounds__(512) void final_kernel(const float* __restrict__ pnum,
                                                    const float* __restrict__ pden,
                                                    float* __restrict__ out) {
    const int tid = threadIdx.x;
    const int lane = tid & 63;
    const int wid = tid >> 6;
    float n = pnum[tid];
    float d = pden[tid];
    #pragma unroll
    for (int off = 32; off > 0; off >>= 1) {
        n += __shfl_down(n, off);
        d += __shfl_down(d, off);
    }
    __shared__ float ln[8], ld[8];
    if (lane == 0) { ln[wid] = n; ld[wid] = d; }
    __syncthreads();
    if (tid == 0) {
        float N = 0.0f, D = 0.0f;
        #pragma unroll
        for (int i = 0; i < 8; ++i) { N += ln[i]; D += ld[i]; }
        out[0] = N / (D + 1e-9f);
    }
}

extern "C" void kernel_launch(void* const* d_in, const int* in_sizes, int n_in,
                              void* d_out, int out_size, void* d_ws, size_t ws_size,
                              hipStream_t stream) {
    const float* states = (const float*)d_in[0];
    const float* rmask  = (const float*)d_in[1];
    const int*   rpos   = (const int*)d_in[2];
    float* out = (float*)d_out;

    float* ws   = (float*)d_ws;
    float* pnum = ws;          // NBLK floats
    float* pden = ws + NBLK;   // NBLK floats

    fused_kernel<<<NBLK, 256, 0, stream>>>(states, rmask, rpos, pnum, pden);
    final_kernel<<<1, 512, 0, stream>>>(pnum, pden, out);
}